// Round 4
// baseline (3333.717 us; speedup 1.0000x reference)
//
#include <hip/hip_runtime.h>
#include <cmath>

constexpr int NB   = 16;      // batch
constexpr int NPTS = 10000;   // points per batch
constexpr int NBN  = NB * NPTS;   // 160000
constexpr int NS_ITERS = 18;

// ---------------------------------------------------------------------------
// Layer 0: 3 -> 64, no input BN
// ---------------------------------------------------------------------------
__global__ __launch_bounds__(256) void conv0_ker(const float* __restrict__ pts,
                                                 const float* __restrict__ W,
                                                 float* __restrict__ y) {
    int g = blockIdx.x * 256 + threadIdx.x;          // 0..159999
    int b = g / NPTS;
    int n = g - b * NPTS;
    float p0 = pts[3 * (size_t)g + 0];
    float p1 = pts[3 * (size_t)g + 1];
    float p2 = pts[3 * (size_t)g + 2];
    float* yp = y + ((size_t)b * 64) * NPTS + n;
    for (int o = 0; o < 64; ++o) {
        float v = W[3 * o] * p0 + W[3 * o + 1] * p1 + W[3 * o + 2] * p2;
        yp[(size_t)o * NPTS] = v;
    }
}

// ---------------------------------------------------------------------------
// Tiled GEMM conv layer: y[b, ob+o, n] = sum_c W[ob+o, c] * relu(bn(x[b, c, n]))
// Block: 64 outputs x 128 points. K chunked by 32. Grid: (79 ntiles, COUT/64, NB)
// ---------------------------------------------------------------------------
template <int CIN, int COUT>
__global__ __launch_bounds__(256) void conv_gemm(const float* __restrict__ xin,
                                                 const float* __restrict__ ss,
                                                 const float* __restrict__ W,
                                                 float* __restrict__ y) {
    __shared__ float Wl[64][CIN + 1];
    __shared__ float Xl[32][132];

    const int tid = threadIdx.x;
    const int nb  = blockIdx.x * 128;
    const int ob  = blockIdx.y * 64;
    const int b   = blockIdx.z;

#pragma unroll
    for (int i = 0; i < CIN / 4; ++i) {
        int l = i * 256 + tid;
        int o = l / CIN, c = l % CIN;
        Wl[o][c] = W[(size_t)(ob + o) * CIN + c];
    }

    const int o0 = (tid >> 4) * 4;      // 4 output channels per thread
    const int n0 = (tid & 15) * 8;      // 8 points per thread

    float acc[4][8];
#pragma unroll
    for (int i = 0; i < 4; ++i)
#pragma unroll
        for (int j = 0; j < 8; ++j) acc[i][j] = 0.f;

    const int n4 = (tid & 31) * 4;
    const int kk0 = tid >> 5;

    for (int kc = 0; kc < CIN; kc += 32) {
        __syncthreads();
        const float* xbase = xin + ((size_t)(b * CIN + kc)) * NPTS;
#pragma unroll
        for (int i = 0; i < 4; ++i) {
            int kk = kk0 + i * 8;
            int ng = nb + n4;
            float4 v = make_float4(0.f, 0.f, 0.f, 0.f);
            if (ng + 4 <= NPTS) {
                v = *(const float4*)(xbase + (size_t)kk * NPTS + ng);
                float sc = ss[kc + kk], sh = ss[256 + kc + kk];
                v.x = fmaxf(fmaf(v.x, sc, sh), 0.f);
                v.y = fmaxf(fmaf(v.y, sc, sh), 0.f);
                v.z = fmaxf(fmaf(v.z, sc, sh), 0.f);
                v.w = fmaxf(fmaf(v.w, sc, sh), 0.f);
            }
            *(float4*)&Xl[kk][n4] = v;
        }
        __syncthreads();
#pragma unroll
        for (int k = 0; k < 32; ++k) {
            float w0 = Wl[o0 + 0][kc + k];
            float w1 = Wl[o0 + 1][kc + k];
            float w2 = Wl[o0 + 2][kc + k];
            float w3 = Wl[o0 + 3][kc + k];
            float4 xa = *(const float4*)&Xl[k][n0];
            float4 xb = *(const float4*)&Xl[k][n0 + 4];
            float xv[8] = {xa.x, xa.y, xa.z, xa.w, xb.x, xb.y, xb.z, xb.w};
#pragma unroll
            for (int j = 0; j < 8; ++j) {
                acc[0][j] = fmaf(w0, xv[j], acc[0][j]);
                acc[1][j] = fmaf(w1, xv[j], acc[1][j]);
                acc[2][j] = fmaf(w2, xv[j], acc[2][j]);
                acc[3][j] = fmaf(w3, xv[j], acc[3][j]);
            }
        }
    }

    const int ng = nb + n0;
#pragma unroll
    for (int i = 0; i < 4; ++i) {
        float* row = y + ((size_t)(b * COUT + ob + o0 + i)) * NPTS + ng;
        if (ng + 8 <= NPTS) {
            *(float4*)row       = make_float4(acc[i][0], acc[i][1], acc[i][2], acc[i][3]);
            *(float4*)(row + 4) = make_float4(acc[i][4], acc[i][5], acc[i][6], acc[i][7]);
        } else {
#pragma unroll
            for (int j = 0; j < 8; ++j)
                if (ng + j < NPTS) row[j] = acc[i][j];
        }
    }
}

// ---------------------------------------------------------------------------
// Per-channel sum / sumsq over (batch, points)  -> stats[c], stats[C+c]
// ---------------------------------------------------------------------------
__global__ void chan_stats(const float* __restrict__ y, int C, float* __restrict__ stats) {
    int c = blockIdx.x, b = blockIdx.y, t = threadIdx.x;
    const float* p = y + ((size_t)(b * C + c)) * NPTS;
    float s = 0.f, q = 0.f;
    for (int n = t; n < NPTS; n += 256) {
        float v = p[n];
        s += v;
        q = fmaf(v, v, q);
    }
    for (int off = 32; off; off >>= 1) {
        s += __shfl_down(s, off);
        q += __shfl_down(q, off);
    }
    __shared__ float ls[4], lq[4];
    if ((t & 63) == 0) { ls[t >> 6] = s; lq[t >> 6] = q; }
    __syncthreads();
    if (t == 0) {
        atomicAdd(&stats[c],     ls[0] + ls[1] + ls[2] + ls[3]);
        atomicAdd(&stats[C + c], lq[0] + lq[1] + lq[2] + lq[3]);
    }
}

__global__ void bn_finalize(const float* __restrict__ stats, const float* __restrict__ g,
                            const float* __restrict__ bi, int C, float* __restrict__ ss) {
    int c = threadIdx.x;
    if (c < C) {
        float mu  = stats[c] * (1.f / NBN);
        float var = stats[C + c] * (1.f / NBN) - mu * mu;
        float r = rsqrtf(var + 1e-5f);
        float s = g[c] * r;
        ss[c] = s;
        ss[256 + c] = bi[c] - mu * s;
    }
}

// ---------------------------------------------------------------------------
// Per-batch channel sums of final features f = relu(bn(y4))
// ---------------------------------------------------------------------------
__global__ void fsum_ker(const float* __restrict__ y4, const float* __restrict__ ss,
                         float* __restrict__ fsumb) {
    int c = blockIdx.x, b = blockIdx.y, t = threadIdx.x;
    const float* p = y4 + ((size_t)(b * 256 + c)) * NPTS;
    float sc = ss[c], sh = ss[256 + c];
    float s = 0.f;
    for (int n = t; n < NPTS; n += 256) {
        float v = fmaf(p[n], sc, sh);
        s += fmaxf(v, 0.f);
    }
    for (int off = 32; off; off >>= 1) s += __shfl_down(s, off);
    __shared__ float ls[4];
    if ((t & 63) == 0) ls[t >> 6] = s;
    __syncthreads();
    if (t == 0) fsumb[b * 256 + c] = ls[0] + ls[1] + ls[2] + ls[3];
}

// ---------------------------------------------------------------------------
// Raw second moment: covM[b] += F_b^T F_b  (128x128 tiles, N split in 16 chunks)
// grid: (16 chunks, 4 tiles, 16 batches) = 1024 blocks
// ---------------------------------------------------------------------------
__global__ __launch_bounds__(256) void cov_ker(const float* __restrict__ y4,
                                               const float* __restrict__ ss,
                                               float* __restrict__ covM) {
    int chunk = blockIdx.x;
    int tile  = blockIdx.y;
    int b     = blockIdx.z;
    int ti = tile >> 1, tj = tile & 1;
    int t = threadIdx.x;
    __shared__ float At[2][32][132];   // [half][point][channel], padded
    float acc[8][8];
#pragma unroll
    for (int i = 0; i < 8; ++i)
#pragma unroll
        for (int j = 0; j < 8; ++j) acc[i][j] = 0.f;

    const int CHN = 625;               // points per chunk (16*625 = 10000)
    int n0c = chunk * CHN;
    int r0 = (t & 15) * 8, c0 = (t >> 4) * 8;
    for (int pp = 0; pp < 20; ++pp) {
        int base = pp * 32;
        __syncthreads();
#pragma unroll
        for (int half = 0; half < 2; ++half) {
            int panel = (half ? tj : ti) * 128;
#pragma unroll
            for (int i = 0; i < 16; ++i) {
                int l = i * 256 + t;
                int c = l >> 5, p = l & 31;
                float v = 0.f;
                if (base + p < CHN) {
                    float raw = y4[((size_t)(b * 256 + panel + c)) * NPTS + n0c + base + p];
                    raw = fmaf(raw, ss[panel + c], ss[256 + panel + c]);
                    v = fmaxf(raw, 0.f);
                }
                At[half][p][c] = v;
            }
        }
        __syncthreads();
#pragma unroll 4
        for (int p = 0; p < 32; ++p) {
            // vectorized LDS reads: 4x b128 instead of 16x b32
            float4 ar0 = *(const float4*)&At[0][p][r0];
            float4 ar1 = *(const float4*)&At[0][p][r0 + 4];
            float4 ac0 = *(const float4*)&At[1][p][c0];
            float4 ac1 = *(const float4*)&At[1][p][c0 + 4];
            float ar[8] = {ar0.x, ar0.y, ar0.z, ar0.w, ar1.x, ar1.y, ar1.z, ar1.w};
            float ac[8] = {ac0.x, ac0.y, ac0.z, ac0.w, ac1.x, ac1.y, ac1.z, ac1.w};
#pragma unroll
            for (int i = 0; i < 8; ++i)
#pragma unroll
                for (int j = 0; j < 8; ++j) acc[i][j] = fmaf(ar[i], ac[j], acc[i][j]);
        }
    }
#pragma unroll
    for (int i = 0; i < 8; ++i)
#pragma unroll
        for (int j = 0; j < 8; ++j) {
            size_t idx = ((size_t)b << 16) + (size_t)(ti * 128 + r0 + i) * 256 + tj * 128 + c0 + j;
            atomicAdd(&covM[idx], acc[i][j]);
        }
}

// ---------------------------------------------------------------------------
// cov = M/N - m (.) fbar^T - fbar (.) m^T + m m^T ; trace via diagonal atomics
// ---------------------------------------------------------------------------
__global__ void covfin_ker(const float* __restrict__ covM, const float* __restrict__ fsumb,
                           float* __restrict__ Y0, float* __restrict__ trace) {
    int r = blockIdx.x, b = blockIdx.y, c = threadIdx.x;
    float fbr = fsumb[b * 256 + r] * (1.f / NPTS);
    float fbc = fsumb[b * 256 + c] * (1.f / NPTS);
    float mr = 0.f, mc = 0.f;
    for (int q = 0; q < NB; ++q) {
        mr += fsumb[q * 256 + r];
        mc += fsumb[q * 256 + c];
    }
    mr *= (1.f / NBN);
    mc *= (1.f / NBN);
    size_t idx = ((size_t)b << 16) + ((size_t)r << 8) + c;
    float v = covM[idx] * (1.f / NPTS) - fbr * mc - mr * fbc + mr * mc;
    Y0[idx] = v;
    if (c == r) atomicAdd(&trace[b], v);
}

__global__ void ns_init(float* __restrict__ Y0, float* __restrict__ Z0,
                        const float* __restrict__ trace) {
    int i = blockIdx.x * 256 + threadIdx.x;   // 16*65536 total
    int b = i >> 16, rc = i & 65535;
    float inv = 1.f / trace[b];
    Y0[i] *= inv;
    Z0[i] = ((rc >> 8) == (rc & 255)) ? 1.f : 0.f;
}

// ---------------------------------------------------------------------------
// 256x256 batched GEMM tile body: O = diag*I + scale*(A.B), 64x64 tiles
// float4 LDS reads: 2x b128 + 16 FMA per k-step
// ---------------------------------------------------------------------------
__device__ __forceinline__ void gemm_body(const float* __restrict__ Ab,
                                          const float* __restrict__ Bb,
                                          float* __restrict__ Ob,
                                          float scale, float diag, int tile, int t,
                                          float (*Al)[68], float (*Bl)[68]) {
    int tr = (tile >> 2) * 64, tc = (tile & 3) * 64;
    int r0 = (t & 15) * 4, c0 = (t >> 4) * 4;
    float acc[4][4];
#pragma unroll
    for (int i = 0; i < 4; ++i)
#pragma unroll
        for (int j = 0; j < 4; ++j) acc[i][j] = 0.f;

    for (int kc = 0; kc < 256; kc += 64) {
        __syncthreads();
#pragma unroll
        for (int i = 0; i < 16; ++i) {
            int l = i * 256 + t;
            int ra = l >> 6, ka = l & 63;
            Al[ka][ra] = Ab[(size_t)(tr + ra) * 256 + kc + ka];
            Bl[ra][ka] = Bb[(size_t)(kc + ra) * 256 + tc + ka];  // ra=k, ka=c
        }
        __syncthreads();
#pragma unroll 8
        for (int k = 0; k < 64; ++k) {
            float4 a4 = *(const float4*)&Al[k][r0];
            float4 b4 = *(const float4*)&Bl[k][c0];
            float av[4] = {a4.x, a4.y, a4.z, a4.w};
            float bv[4] = {b4.x, b4.y, b4.z, b4.w};
#pragma unroll
            for (int i = 0; i < 4; ++i)
#pragma unroll
                for (int j = 0; j < 4; ++j)
                    acc[i][j] = fmaf(av[i], bv[j], acc[i][j]);
        }
    }
#pragma unroll
    for (int i = 0; i < 4; ++i)
#pragma unroll
        for (int j = 0; j < 4; ++j) {
            int r = tr + r0 + i, c = tc + c0 + j;
            float v = scale * acc[i][j] + ((r == c) ? diag : 0.f);
            Ob[(size_t)r * 256 + c] = v;
        }
}

__global__ __launch_bounds__(256) void ns_gemm(const float* __restrict__ A,
                                               const float* __restrict__ B,
                                               float* __restrict__ O,
                                               float scale, float diag) {
    __shared__ float Al[64][68], Bl[64][68];
    size_t off = (size_t)blockIdx.y << 16;
    gemm_body(A + off, B + off, O + off, scale, diag, blockIdx.x, threadIdx.x, Al, Bl);
}

__global__ __launch_bounds__(256) void ns_gemm_pair(const float* __restrict__ Y,
                                                    const float* __restrict__ Mm,
                                                    const float* __restrict__ Z,
                                                    float* __restrict__ Yn,
                                                    float* __restrict__ Zn) {
    __shared__ float Al[64][68], Bl[64][68];
    size_t off = (size_t)blockIdx.y << 16;
    if (blockIdx.z == 0)
        gemm_body(Y + off, Mm + off, Yn + off, 0.5f, 0.f, blockIdx.x, threadIdx.x, Al, Bl);
    else
        gemm_body(Mm + off, Z + off, Zn + off, 0.5f, 0.f, blockIdx.x, threadIdx.x, Al, Bl);
}

// ---------------------------------------------------------------------------
// FC: outpre[b,o] += sum_k sqrt(trace[b])*Yf[b,k] * Wfc[o,k]
// ---------------------------------------------------------------------------
__global__ __launch_bounds__(256) void fc_ker(const float* __restrict__ Yf,
                                              const float* __restrict__ trace,
                                              const float* __restrict__ Wfc,
                                              float* __restrict__ outpre) {
    int kc = blockIdx.x;
    int ot = blockIdx.y;
    int t = threadIdx.x;
    __shared__ float Wl[64][129];
    __shared__ float Vl[16][129];
#pragma unroll
    for (int i = 0; i < 32; ++i) {
        int l = i * 256 + t;
        int o = l >> 7, k = l & 127;
        Wl[o][k] = Wfc[(size_t)(ot * 64 + o) * 65536 + kc * 128 + k];
    }
#pragma unroll
    for (int i = 0; i < 8; ++i) {
        int l = i * 256 + t;
        int bb = l >> 7, k = l & 127;
        Vl[bb][k] = sqrtf(trace[bb]) * Yf[((size_t)bb << 16) + kc * 128 + k];
    }
    __syncthreads();
    int ol = t & 63, bg = t >> 6;
    float a0 = 0.f, a1 = 0.f, a2 = 0.f, a3 = 0.f;
    for (int k = 0; k < 128; ++k) {
        float w = Wl[ol][k];
        a0 = fmaf(w, Vl[bg * 4 + 0][k], a0);
        a1 = fmaf(w, Vl[bg * 4 + 1][k], a1);
        a2 = fmaf(w, Vl[bg * 4 + 2][k], a2);
        a3 = fmaf(w, Vl[bg * 4 + 3][k], a3);
    }
    int o = ot * 64 + ol;
    atomicAdd(&outpre[(bg * 4 + 0) * 256 + o], a0);
    atomicAdd(&outpre[(bg * 4 + 1) * 256 + o], a1);
    atomicAdd(&outpre[(bg * 4 + 2) * 256 + o], a2);
    atomicAdd(&outpre[(bg * 4 + 3) * 256 + o], a3);
}

__global__ void norm_ker(const float* __restrict__ outpre, const float* __restrict__ bfc,
                         float* __restrict__ dout) {
    int b = blockIdx.x, t = threadIdx.x;
    float v = outpre[b * 256 + t] + bfc[t];
    float q = v * v;
    for (int off = 32; off; off >>= 1) q += __shfl_xor(q, off);
    __shared__ float lq[4];
    __shared__ float snorm;
    if ((t & 63) == 0) lq[t >> 6] = q;
    __syncthreads();
    if (t == 0) snorm = fmaxf(sqrtf(lq[0] + lq[1] + lq[2] + lq[3]), 1e-12f);
    __syncthreads();
    dout[b * 256 + t] = v / snorm;
}

// ---------------------------------------------------------------------------
// Workspace layout (floats), total ~234 MiB — see round-1 notes.
// ---------------------------------------------------------------------------
extern "C" void kernel_launch(void* const* d_in, const int* in_sizes, int n_in,
                              void* d_out, int out_size, void* d_ws, size_t ws_size,
                              hipStream_t stream) {
    (void)in_sizes; (void)n_in; (void)out_size; (void)ws_size;
    const float* pts = (const float*)d_in[0];
    const float* Wm[5]; const float* gm[5]; const float* bm[5];
    for (int i = 0; i < 5; ++i) {
        Wm[i] = (const float*)d_in[1 + 3 * i];
        gm[i] = (const float*)d_in[2 + 3 * i];
        bm[i] = (const float*)d_in[3 + 3 * i];
    }
    const float* Wfc = (const float*)d_in[16];
    const float* bfc = (const float*)d_in[17];

    float* ws     = (float*)d_ws;
    float* stats  = ws;                  // 2560
    float* fsumb  = ws + 2560;           // 4096
    float* trace  = ws + 6656;           // 16
    float* outpre = ws + 6672;           // 4096
    float* ss     = ws + 10768;          // 2560
    float* R      = ws + 16384;          // 256ch fp32: 40,960,000 floats (y4)
    float* P      = R;                   // 64ch view (L0/L2 out)
    float* Q      = R + (size_t)NB * 256 * NPTS;   // 128ch: 20,480,000 floats
    // NS-phase aliases of the (then-dead) Q region:
    float* covM   = Q;
    float* Y0     = Q + 1048576;
    float* Y1     = Y0 + 1048576;
    float* Z0     = Y1 + 1048576;
    float* Z1     = Z0 + 1048576;
    float* Mb     = Z1 + 1048576;

    hipMemsetAsync(ws, 0, 16384 * sizeof(float), stream);

    // Layer 0 (3 -> 64)
    conv0_ker<<<dim3(NBN / 256), dim3(256), 0, stream>>>(pts, Wm[0], P);
    chan_stats<<<dim3(64, NB), dim3(256), 0, stream>>>(P, 64, stats);
    bn_finalize<<<dim3(1), dim3(256), 0, stream>>>(stats, gm[0], bm[0], 64, ss);
    // Layer 1 (64 -> 64)
    conv_gemm<64, 64><<<dim3(79, 1, NB), dim3(256), 0, stream>>>(P, ss, Wm[1], Q);
    chan_stats<<<dim3(64, NB), dim3(256), 0, stream>>>(Q, 64, stats + 512);
    bn_finalize<<<dim3(1), dim3(256), 0, stream>>>(stats + 512, gm[1], bm[1], 64, ss + 512);
    // Layer 2 (64 -> 64)
    conv_gemm<64, 64><<<dim3(79, 1, NB), dim3(256), 0, stream>>>(Q, ss + 512, Wm[2], P);
    chan_stats<<<dim3(64, NB), dim3(256), 0, stream>>>(P, 64, stats + 1024);
    bn_finalize<<<dim3(1), dim3(256), 0, stream>>>(stats + 1024, gm[2], bm[2], 64, ss + 1024);
    // Layer 3 (64 -> 128)
    conv_gemm<64, 128><<<dim3(79, 2, NB), dim3(256), 0, stream>>>(P, ss + 1024, Wm[3], Q);
    chan_stats<<<dim3(128, NB), dim3(256), 0, stream>>>(Q, 128, stats + 1536);
    bn_finalize<<<dim3(1), dim3(256), 0, stream>>>(stats + 1536, gm[3], bm[3], 128, ss + 1536);
    // Layer 4 (128 -> 256); writes R (P is dead now)
    conv_gemm<128, 256><<<dim3(79, 4, NB), dim3(256), 0, stream>>>(Q, ss + 1536, Wm[4], R);
    chan_stats<<<dim3(256, NB), dim3(256), 0, stream>>>(R, 256, stats + 2048);
    bn_finalize<<<dim3(1), dim3(256), 0, stream>>>(stats + 2048, gm[4], bm[4], 256, ss + 2048);

    // Covariance path (Q dead; its region now hosts covM/NS buffers)
    fsum_ker<<<dim3(256, NB), dim3(256), 0, stream>>>(R, ss + 2048, fsumb);
    hipMemsetAsync(covM, 0, 1048576 * sizeof(float), stream);
    cov_ker<<<dim3(16, 4, NB), dim3(256), 0, stream>>>(R, ss + 2048, covM);
    covfin_ker<<<dim3(256, NB), dim3(256), 0, stream>>>(covM, fsumb, Y0, trace);
    ns_init<<<dim3(4096), dim3(256), 0, stream>>>(Y0, Z0, trace);

    // Newton–Schulz iterations for principal sqrt
    float* Yc = Y0; float* Zc = Z0; float* Yn = Y1; float* Zn = Z1;
    for (int it = 0; it < NS_ITERS; ++it) {
        ns_gemm<<<dim3(16, NB), dim3(256), 0, stream>>>(Zc, Yc, Mb, -1.f, 3.f);
        ns_gemm_pair<<<dim3(16, NB, 2), dim3(256), 0, stream>>>(Yc, Mb, Zc, Yn, Zn);
        float* ty = Yc; Yc = Yn; Yn = ty;
        float* tz = Zc; Zc = Zn; Zn = tz;
    }

    fc_ker<<<dim3(512, 4), dim3(256), 0, stream>>>(Yc, trace, Wfc, outpre);
    norm_ker<<<dim3(NB), dim3(256), 0, stream>>>(outpre, bfc, (float*)d_out);
}

// Round 6
// 2578.002 us; speedup vs baseline: 1.2931x; 1.2931x over previous
//
#include <hip/hip_runtime.h>
#include <cmath>

constexpr int NB   = 16;      // batch
constexpr int NPTS = 10000;   // points per batch
constexpr int NBN  = NB * NPTS;   // 160000
constexpr int NS_ITERS = 18;
constexpr int COV_CHUNKS = 5;     // 2000 points each

typedef __bf16 bf16x8 __attribute__((ext_vector_type(8)));
typedef float  f32x4  __attribute__((ext_vector_type(4)));
typedef unsigned short ushort4v __attribute__((ext_vector_type(4)));

// ---------------------------------------------------------------------------
// Layer 0: 3 -> 64, no input BN
// ---------------------------------------------------------------------------
__global__ __launch_bounds__(256) void conv0_ker(const float* __restrict__ pts,
                                                 const float* __restrict__ W,
                                                 float* __restrict__ y) {
    int g = blockIdx.x * 256 + threadIdx.x;          // 0..159999
    int b = g / NPTS;
    int n = g - b * NPTS;
    float p0 = pts[3 * (size_t)g + 0];
    float p1 = pts[3 * (size_t)g + 1];
    float p2 = pts[3 * (size_t)g + 2];
    float* yp = y + ((size_t)b * 64) * NPTS + n;
    for (int o = 0; o < 64; ++o) {
        float v = W[3 * o] * p0 + W[3 * o + 1] * p1 + W[3 * o + 2] * p2;
        yp[(size_t)o * NPTS] = v;
    }
}

// ---------------------------------------------------------------------------
// Tiled GEMM conv layer: y[b, ob+o, n] = sum_c W[ob+o, c] * relu(bn(x[b, c, n]))
// ---------------------------------------------------------------------------
template <int CIN, int COUT>
__global__ __launch_bounds__(256) void conv_gemm(const float* __restrict__ xin,
                                                 const float* __restrict__ ss,
                                                 const float* __restrict__ W,
                                                 float* __restrict__ y) {
    __shared__ float Wl[64][CIN + 1];
    __shared__ float Xl[32][132];

    const int tid = threadIdx.x;
    const int nb  = blockIdx.x * 128;
    const int ob  = blockIdx.y * 64;
    const int b   = blockIdx.z;

#pragma unroll
    for (int i = 0; i < CIN / 4; ++i) {
        int l = i * 256 + tid;
        int o = l / CIN, c = l % CIN;
        Wl[o][c] = W[(size_t)(ob + o) * CIN + c];
    }

    const int o0 = (tid >> 4) * 4;
    const int n0 = (tid & 15) * 8;

    float acc[4][8];
#pragma unroll
    for (int i = 0; i < 4; ++i)
#pragma unroll
        for (int j = 0; j < 8; ++j) acc[i][j] = 0.f;

    const int n4 = (tid & 31) * 4;
    const int kk0 = tid >> 5;

    for (int kc = 0; kc < CIN; kc += 32) {
        __syncthreads();
        const float* xbase = xin + ((size_t)(b * CIN + kc)) * NPTS;
#pragma unroll
        for (int i = 0; i < 4; ++i) {
            int kk = kk0 + i * 8;
            int ng = nb + n4;
            float4 v = make_float4(0.f, 0.f, 0.f, 0.f);
            if (ng + 4 <= NPTS) {
                v = *(const float4*)(xbase + (size_t)kk * NPTS + ng);
                float sc = ss[kc + kk], sh = ss[256 + kc + kk];
                v.x = fmaxf(fmaf(v.x, sc, sh), 0.f);
                v.y = fmaxf(fmaf(v.y, sc, sh), 0.f);
                v.z = fmaxf(fmaf(v.z, sc, sh), 0.f);
                v.w = fmaxf(fmaf(v.w, sc, sh), 0.f);
            }
            *(float4*)&Xl[kk][n4] = v;
        }
        __syncthreads();
#pragma unroll
        for (int k = 0; k < 32; ++k) {
            float w0 = Wl[o0 + 0][kc + k];
            float w1 = Wl[o0 + 1][kc + k];
            float w2 = Wl[o0 + 2][kc + k];
            float w3 = Wl[o0 + 3][kc + k];
            float4 xa = *(const float4*)&Xl[k][n0];
            float4 xb = *(const float4*)&Xl[k][n0 + 4];
            float xv[8] = {xa.x, xa.y, xa.z, xa.w, xb.x, xb.y, xb.z, xb.w};
#pragma unroll
            for (int j = 0; j < 8; ++j) {
                acc[0][j] = fmaf(w0, xv[j], acc[0][j]);
                acc[1][j] = fmaf(w1, xv[j], acc[1][j]);
                acc[2][j] = fmaf(w2, xv[j], acc[2][j]);
                acc[3][j] = fmaf(w3, xv[j], acc[3][j]);
            }
        }
    }

    const int ng = nb + n0;
#pragma unroll
    for (int i = 0; i < 4; ++i) {
        float* row = y + ((size_t)(b * COUT + ob + o0 + i)) * NPTS + ng;
        if (ng + 8 <= NPTS) {
            *(float4*)row       = make_float4(acc[i][0], acc[i][1], acc[i][2], acc[i][3]);
            *(float4*)(row + 4) = make_float4(acc[i][4], acc[i][5], acc[i][6], acc[i][7]);
        } else {
#pragma unroll
            for (int j = 0; j < 8; ++j)
                if (ng + j < NPTS) row[j] = acc[i][j];
        }
    }
}

// ---------------------------------------------------------------------------
// Per-channel sum / sumsq over (batch, points)  -> stats[c], stats[C+c]
// ---------------------------------------------------------------------------
__global__ void chan_stats(const float* __restrict__ y, int C, float* __restrict__ stats) {
    int c = blockIdx.x, b = blockIdx.y, t = threadIdx.x;
    const float* p = y + ((size_t)(b * C + c)) * NPTS;
    float s = 0.f, q = 0.f;
    for (int n = t; n < NPTS; n += 256) {
        float v = p[n];
        s += v;
        q = fmaf(v, v, q);
    }
    for (int off = 32; off; off >>= 1) {
        s += __shfl_down(s, off);
        q += __shfl_down(q, off);
    }
    __shared__ float ls[4], lq[4];
    if ((t & 63) == 0) { ls[t >> 6] = s; lq[t >> 6] = q; }
    __syncthreads();
    if (t == 0) {
        atomicAdd(&stats[c],     ls[0] + ls[1] + ls[2] + ls[3]);
        atomicAdd(&stats[C + c], lq[0] + lq[1] + lq[2] + lq[3]);
    }
}

__global__ void bn_finalize(const float* __restrict__ stats, const float* __restrict__ g,
                            const float* __restrict__ bi, int C, float* __restrict__ ss) {
    int c = threadIdx.x;
    if (c < C) {
        float mu  = stats[c] * (1.f / NBN);
        float var = stats[C + c] * (1.f / NBN) - mu * mu;
        float r = rsqrtf(var + 1e-5f);
        float s = g[c] * r;
        ss[c] = s;
        ss[256 + c] = bi[c] - mu * s;
    }
}

// ---------------------------------------------------------------------------
// Per-batch channel sums of final features f = relu(bn(y4))
// ---------------------------------------------------------------------------
__global__ void fsum_ker(const float* __restrict__ y4, const float* __restrict__ ss,
                         float* __restrict__ fsumb) {
    int c = blockIdx.x, b = blockIdx.y, t = threadIdx.x;
    const float* p = y4 + ((size_t)(b * 256 + c)) * NPTS;
    float sc = ss[c], sh = ss[256 + c];
    float s = 0.f;
    for (int n = t; n < NPTS; n += 256) {
        float v = fmaf(p[n], sc, sh);
        s += fmaxf(v, 0.f);
    }
    for (int off = 32; off; off >>= 1) s += __shfl_down(s, off);
    __shared__ float ls[4];
    if ((t & 63) == 0) ls[t >> 6] = s;
    __syncthreads();
    if (t == 0) fsumb[b * 256 + c] = ls[0] + ls[1] + ls[2] + ls[3];
}

// ---------------------------------------------------------------------------
// Split-bf16 MFMA second moment: covP[chunk][b] tile += F F^T over 2000 pts.
// grid: (5 chunks, 3 tiles{(0,0),(1,1),(0,1)}, 16 batches) = 240 blocks.
// ---------------------------------------------------------------------------
__device__ __forceinline__ unsigned short bf_hi(float f) {
    return (unsigned short)(__float_as_uint(f) >> 16);      // truncate to bf16
}
__device__ __forceinline__ unsigned short bf_lo(float f) {
    float hf = __uint_as_float(__float_as_uint(f) & 0xFFFF0000u);
    return (unsigned short)(__float_as_uint(f - hf) >> 16); // residual as bf16
}

__global__ __launch_bounds__(256) void cov_mfma(const float* __restrict__ y4,
                                                const float* __restrict__ ss,
                                                float* __restrict__ covP) {
    __shared__ unsigned short pan[2][2][4096];   // [panel][hi/lo][8 frag-tiles * 512]

    const int chunk = blockIdx.x;
    const int tile  = blockIdx.y;
    const int b     = blockIdx.z;
    const int ti = (tile == 1) ? 1 : 0;
    const int tj = (tile == 0) ? 0 : 1;
    const int npan = (tile == 2) ? 2 : 1;

    const int tid  = threadIdx.x;
    const int lane = tid & 63;
    const int w    = tid >> 6;
    const int wr   = w & 1, wc = w >> 1;

    const int n0c = chunk * 2000;

    f32x4 acc[4][4];
#pragma unroll
    for (int m = 0; m < 4; ++m)
#pragma unroll
        for (int n = 0; n < 4; ++n) acc[m][n] = (f32x4){0.f, 0.f, 0.f, 0.f};

    // staging assignment: 8 point-groups (4 pts) x 32 channel-bases
    const int g   = tid & 7;
    const int chb = tid >> 3;          // 0..31
    const int p4  = g * 4;             // point offset in 32-chunk
    const int q   = p4 >> 3, j0 = p4 & 7;

#pragma unroll 1
    for (int kk = 0; kk < 63; ++kk) {          // 63*32 = 2016 >= 2000
        const int nbase = n0c + kk * 32;
        __syncthreads();
        for (int p = 0; p < npan; ++p) {
            const int pcb = (p ? tj : ti) * 128;
#pragma unroll
            for (int i = 0; i < 4; ++i) {
                const int ch = chb + 32 * i;
                float4 v = make_float4(0.f, 0.f, 0.f, 0.f);
                if (kk * 32 + p4 < 2000) {
                    v = *(const float4*)(y4 + ((size_t)(b * 256 + pcb + ch)) * NPTS + nbase + p4);
                    float sc = ss[pcb + ch], sh = ss[256 + pcb + ch];
                    v.x = fmaxf(fmaf(v.x, sc, sh), 0.f);
                    v.y = fmaxf(fmaf(v.y, sc, sh), 0.f);
                    v.z = fmaxf(fmaf(v.z, sc, sh), 0.f);
                    v.w = fmaxf(fmaf(v.w, sc, sh), 0.f);
                }
                ushort4v h4, l4;
                h4[0] = bf_hi(v.x); l4[0] = bf_lo(v.x);
                h4[1] = bf_hi(v.y); l4[1] = bf_lo(v.y);
                h4[2] = bf_hi(v.z); l4[2] = bf_lo(v.z);
                h4[3] = bf_hi(v.w); l4[3] = bf_lo(v.w);
                const int addr = (ch >> 4) * 512 + (q * 16 + (ch & 15)) * 8 + j0;
                *(ushort4v*)&pan[p][0][addr] = h4;
                *(ushort4v*)&pan[p][1][addr] = l4;
            }
        }
        __syncthreads();

        const unsigned short* Ah = pan[0][0];
        const unsigned short* Al = pan[0][1];
        const unsigned short* Bh = pan[npan - 1][0];
        const unsigned short* Bl = pan[npan - 1][1];

        bf16x8 ah[4], al[4], bh[4], bl[4];
#pragma unroll
        for (int m = 0; m < 4; ++m) {
            int t8 = (wr * 4 + m) * 512 + lane * 8;
            ah[m] = *(const bf16x8*)&Ah[t8];
            al[m] = *(const bf16x8*)&Al[t8];
        }
#pragma unroll
        for (int n = 0; n < 4; ++n) {
            int t8 = (wc * 4 + n) * 512 + lane * 8;
            bh[n] = *(const bf16x8*)&Bh[t8];
            bl[n] = *(const bf16x8*)&Bl[t8];
        }
#pragma unroll
        for (int m = 0; m < 4; ++m)
#pragma unroll
            for (int n = 0; n < 4; ++n) {
                acc[m][n] = __builtin_amdgcn_mfma_f32_16x16x32_bf16(ah[m], bh[n], acc[m][n], 0, 0, 0);
                acc[m][n] = __builtin_amdgcn_mfma_f32_16x16x32_bf16(ah[m], bl[n], acc[m][n], 0, 0, 0);
                acc[m][n] = __builtin_amdgcn_mfma_f32_16x16x32_bf16(al[m], bh[n], acc[m][n], 0, 0, 0);
            }
    }

    // epilogue: plain stores to per-chunk partial buffer (no atomics)
    float* outp = covP + ((size_t)(chunk * NB + b) << 16);
    const int rowb = ti * 128 + wr * 64;
    const int colb = tj * 128 + wc * 64;
#pragma unroll
    for (int m = 0; m < 4; ++m)
#pragma unroll
        for (int n = 0; n < 4; ++n)
#pragma unroll
            for (int r = 0; r < 4; ++r) {
                int row = rowb + m * 16 + (lane >> 4) * 4 + r;
                int col = colb + n * 16 + (lane & 15);
                outp[(row << 8) + col] = acc[m][n][r];
            }
}

// ---------------------------------------------------------------------------
// cov = (sum_q covP[q])/N - m fbar^T - fbar m^T + m m^T ; mirror tile (1,0)
// ---------------------------------------------------------------------------
__global__ void covfin_ker(const float* __restrict__ covP, const float* __restrict__ fsumb,
                           float* __restrict__ Y0, float* __restrict__ trace) {
    int r = blockIdx.x, b = blockIdx.y, c = threadIdx.x;
    float fbr = fsumb[b * 256 + r] * (1.f / NPTS);
    float fbc = fsumb[b * 256 + c] * (1.f / NPTS);
    float mr = 0.f, mc = 0.f;
    for (int q = 0; q < NB; ++q) {
        mr += fsumb[q * 256 + r];
        mc += fsumb[q * 256 + c];
    }
    mr *= (1.f / NBN);
    mc *= (1.f / NBN);
    int rr = r, cc = c;
    if (r >= 128 && c < 128) { rr = c; cc = r; }   // tile (1,0) mirrored from (0,1)
    size_t base = ((size_t)b << 16) + ((size_t)rr << 8) + cc;
    float m5 = 0.f;
#pragma unroll
    for (int q = 0; q < COV_CHUNKS; ++q)
        m5 += covP[(size_t)q * (NB * 65536) + base];
    float v = m5 * (1.f / NPTS) - fbr * mc - mr * fbc + mr * mc;
    Y0[((size_t)b << 16) + ((size_t)r << 8) + c] = v;
    if (c == r) atomicAdd(&trace[b], v);
}

__global__ void ns_init(float* __restrict__ Y0, float* __restrict__ Z0,
                        const float* __restrict__ trace) {
    int i = blockIdx.x * 256 + threadIdx.x;   // 16*65536 total
    int b = i >> 16, rc = i & 65535;
    float inv = 1.f / trace[b];
    Y0[i] *= inv;
    Z0[i] = ((rc >> 8) == (rc & 255)) ? 1.f : 0.f;
}

// ---------------------------------------------------------------------------
// 256x256 batched GEMM tile body: O = diag*I + scale*(A.B), 64x64 tiles
// ---------------------------------------------------------------------------
__device__ __forceinline__ void gemm_body(const float* __restrict__ Ab,
                                          const float* __restrict__ Bb,
                                          float* __restrict__ Ob,
                                          float scale, float diag, int tile, int t,
                                          float (*Al)[68], float (*Bl)[68]) {
    int tr = (tile >> 2) * 64, tc = (tile & 3) * 64;
    int r0 = (t & 15) * 4, c0 = (t >> 4) * 4;
    float acc[4][4];
#pragma unroll
    for (int i = 0; i < 4; ++i)
#pragma unroll
        for (int j = 0; j < 4; ++j) acc[i][j] = 0.f;

    for (int kc = 0; kc < 256; kc += 64) {
        __syncthreads();
#pragma unroll
        for (int i = 0; i < 16; ++i) {
            int l = i * 256 + t;
            int ra = l >> 6, ka = l & 63;
            Al[ka][ra] = Ab[(size_t)(tr + ra) * 256 + kc + ka];
            Bl[ra][ka] = Bb[(size_t)(kc + ra) * 256 + tc + ka];
        }
        __syncthreads();
#pragma unroll 8
        for (int k = 0; k < 64; ++k) {
            float4 a4 = *(const float4*)&Al[k][r0];
            float4 b4 = *(const float4*)&Bl[k][c0];
            float av[4] = {a4.x, a4.y, a4.z, a4.w};
            float bv[4] = {b4.x, b4.y, b4.z, b4.w};
#pragma unroll
            for (int i = 0; i < 4; ++i)
#pragma unroll
                for (int j = 0; j < 4; ++j)
                    acc[i][j] = fmaf(av[i], bv[j], acc[i][j]);
        }
    }
#pragma unroll
    for (int i = 0; i < 4; ++i)
#pragma unroll
        for (int j = 0; j < 4; ++j) {
            int r = tr + r0 + i, c = tc + c0 + j;
            float v = scale * acc[i][j] + ((r == c) ? diag : 0.f);
            Ob[(size_t)r * 256 + c] = v;
        }
}

__global__ __launch_bounds__(256) void ns_gemm(const float* __restrict__ A,
                                               const float* __restrict__ B,
                                               float* __restrict__ O,
                                               float scale, float diag) {
    __shared__ float Al[64][68], Bl[64][68];
    size_t off = (size_t)blockIdx.y << 16;
    gemm_body(A + off, B + off, O + off, scale, diag, blockIdx.x, threadIdx.x, Al, Bl);
}

__global__ __launch_bounds__(256) void ns_gemm_pair(const float* __restrict__ Y,
                                                    const float* __restrict__ Mm,
                                                    const float* __restrict__ Z,
                                                    float* __restrict__ Yn,
                                                    float* __restrict__ Zn) {
    __shared__ float Al[64][68], Bl[64][68];
    size_t off = (size_t)blockIdx.y << 16;
    if (blockIdx.z == 0)
        gemm_body(Y + off, Mm + off, Yn + off, 0.5f, 0.f, blockIdx.x, threadIdx.x, Al, Bl);
    else
        gemm_body(Mm + off, Z + off, Zn + off, 0.5f, 0.f, blockIdx.x, threadIdx.x, Al, Bl);
}

// ---------------------------------------------------------------------------
// FC: outpre[b,o] += sum_k sqrt(trace[b])*Yf[b,k] * Wfc[o,k]
// ---------------------------------------------------------------------------
__global__ __launch_bounds__(256) void fc_ker(const float* __restrict__ Yf,
                                              const float* __restrict__ trace,
                                              const float* __restrict__ Wfc,
                                              float* __restrict__ outpre) {
    int kc = blockIdx.x;
    int ot = blockIdx.y;
    int t = threadIdx.x;
    __shared__ float Wl[64][129];
    __shared__ float Vl[16][129];
#pragma unroll
    for (int i = 0; i < 32; ++i) {
        int l = i * 256 + t;
        int o = l >> 7, k = l & 127;
        Wl[o][k] = Wfc[(size_t)(ot * 64 + o) * 65536 + kc * 128 + k];
    }
#pragma unroll
    for (int i = 0; i < 8; ++i) {
        int l = i * 256 + t;
        int bb = l >> 7, k = l & 127;
        Vl[bb][k] = sqrtf(trace[bb]) * Yf[((size_t)bb << 16) + kc * 128 + k];
    }
    __syncthreads();
    int ol = t & 63, bg = t >> 6;
    float a0 = 0.f, a1 = 0.f, a2 = 0.f, a3 = 0.f;
    for (int k = 0; k < 128; ++k) {
        float w = Wl[ol][k];
        a0 = fmaf(w, Vl[bg * 4 + 0][k], a0);
        a1 = fmaf(w, Vl[bg * 4 + 1][k], a1);
        a2 = fmaf(w, Vl[bg * 4 + 2][k], a2);
        a3 = fmaf(w, Vl[bg * 4 + 3][k], a3);
    }
    int o = ot * 64 + ol;
    atomicAdd(&outpre[(bg * 4 + 0) * 256 + o], a0);
    atomicAdd(&outpre[(bg * 4 + 1) * 256 + o], a1);
    atomicAdd(&outpre[(bg * 4 + 2) * 256 + o], a2);
    atomicAdd(&outpre[(bg * 4 + 3) * 256 + o], a3);
}

__global__ void norm_ker(const float* __restrict__ outpre, const float* __restrict__ bfc,
                         float* __restrict__ dout) {
    int b = blockIdx.x, t = threadIdx.x;
    float v = outpre[b * 256 + t] + bfc[t];
    float q = v * v;
    for (int off = 32; off; off >>= 1) q += __shfl_xor(q, off);
    __shared__ float lq[4];
    __shared__ float snorm;
    if ((t & 63) == 0) lq[t >> 6] = q;
    __syncthreads();
    if (t == 0) snorm = fmaxf(sqrtf(lq[0] + lq[1] + lq[2] + lq[3]), 1e-12f);
    __syncthreads();
    dout[b * 256 + t] = v / snorm;
}

// ---------------------------------------------------------------------------
extern "C" void kernel_launch(void* const* d_in, const int* in_sizes, int n_in,
                              void* d_out, int out_size, void* d_ws, size_t ws_size,
                              hipStream_t stream) {
    (void)in_sizes; (void)n_in; (void)out_size; (void)ws_size;
    const float* pts = (const float*)d_in[0];
    const float* Wm[5]; const float* gm[5]; const float* bm[5];
    for (int i = 0; i < 5; ++i) {
        Wm[i] = (const float*)d_in[1 + 3 * i];
        gm[i] = (const float*)d_in[2 + 3 * i];
        bm[i] = (const float*)d_in[3 + 3 * i];
    }
    const float* Wfc = (const float*)d_in[16];
    const float* bfc = (const float*)d_in[17];

    float* ws     = (float*)d_ws;
    float* stats  = ws;                  // 2560
    float* fsumb  = ws + 2560;           // 4096
    float* trace  = ws + 6656;           // 16
    float* outpre = ws + 6672;           // 4096
    float* ss     = ws + 10768;          // 2560
    float* R      = ws + 16384;          // 256ch fp32: 40,960,000 floats (y4)
    float* P      = R;                   // 64ch view (L0/L2 out)
    float* Q      = R + (size_t)NB * 256 * NPTS;   // 128ch: 20,480,000 floats
    // NS-phase aliases of the (then-dead) Q region:
    float* covP   = Q;                              // 5 * 16 * 65536 = 5,242,880
    float* Y0     = covP + (size_t)COV_CHUNKS * NB * 65536;
    float* Y1     = Y0 + 1048576;
    float* Z0     = Y1 + 1048576;
    float* Z1     = Z0 + 1048576;
    float* Mb     = Z1 + 1048576;        // ends at 10.5M < 20.48M floats of Q

    hipMemsetAsync(ws, 0, 16384 * sizeof(float), stream);

    // Layer 0 (3 -> 64)
    conv0_ker<<<dim3(NBN / 256), dim3(256), 0, stream>>>(pts, Wm[0], P);
    chan_stats<<<dim3(64, NB), dim3(256), 0, stream>>>(P, 64, stats);
    bn_finalize<<<dim3(1), dim3(256), 0, stream>>>(stats, gm[0], bm[0], 64, ss);
    // Layer 1 (64 -> 64)
    conv_gemm<64, 64><<<dim3(79, 1, NB), dim3(256), 0, stream>>>(P, ss, Wm[1], Q);
    chan_stats<<<dim3(64, NB), dim3(256), 0, stream>>>(Q, 64, stats + 512);
    bn_finalize<<<dim3(1), dim3(256), 0, stream>>>(stats + 512, gm[1], bm[1], 64, ss + 512);
    // Layer 2 (64 -> 64)
    conv_gemm<64, 64><<<dim3(79, 1, NB), dim3(256), 0, stream>>>(Q, ss + 512, Wm[2], P);
    chan_stats<<<dim3(64, NB), dim3(256), 0, stream>>>(P, 64, stats + 1024);
    bn_finalize<<<dim3(1), dim3(256), 0, stream>>>(stats + 1024, gm[2], bm[2], 64, ss + 1024);
    // Layer 3 (64 -> 128)
    conv_gemm<64, 128><<<dim3(79, 2, NB), dim3(256), 0, stream>>>(P, ss + 1024, Wm[3], Q);
    chan_stats<<<dim3(128, NB), dim3(256), 0, stream>>>(Q, 128, stats + 1536);
    bn_finalize<<<dim3(1), dim3(256), 0, stream>>>(stats + 1536, gm[3], bm[3], 128, ss + 1536);
    // Layer 4 (128 -> 256); writes R (P is dead now)
    conv_gemm<128, 256><<<dim3(79, 4, NB), dim3(256), 0, stream>>>(Q, ss + 1536, Wm[4], R);
    chan_stats<<<dim3(256, NB), dim3(256), 0, stream>>>(R, 256, stats + 2048);
    bn_finalize<<<dim3(1), dim3(256), 0, stream>>>(stats + 2048, gm[4], bm[4], 256, ss + 2048);

    // Covariance path (Q dead; its region now hosts covP/NS buffers)
    fsum_ker<<<dim3(256, NB), dim3(256), 0, stream>>>(R, ss + 2048, fsumb);
    cov_mfma<<<dim3(COV_CHUNKS, 3, NB), dim3(256), 0, stream>>>(R, ss + 2048, covP);
    covfin_ker<<<dim3(256, NB), dim3(256), 0, stream>>>(covP, fsumb, Y0, trace);
    ns_init<<<dim3(4096), dim3(256), 0, stream>>>(Y0, Z0, trace);

    // Newton–Schulz iterations for principal sqrt
    float* Yc = Y0; float* Zc = Z0; float* Yn = Y1; float* Zn = Z1;
    for (int it = 0; it < NS_ITERS; ++it) {
        ns_gemm<<<dim3(16, NB), dim3(256), 0, stream>>>(Zc, Yc, Mb, -1.f, 3.f);
        ns_gemm_pair<<<dim3(16, NB, 2), dim3(256), 0, stream>>>(Yc, Mb, Zc, Yn, Zn);
        float* ty = Yc; Yc = Yn; Yn = ty;
        float* tz = Zc; Zc = Zn; Zn = tz;
    }

    fc_ker<<<dim3(512, 4), dim3(256), 0, stream>>>(Yc, trace, Wfc, outpre);
    norm_ker<<<dim3(NB), dim3(256), 0, stream>>>(outpre, bfc, (float*)d_out);
}